// Round 1
// baseline (348.786 us; speedup 1.0000x reference)
//
#include <hip/hip_runtime.h>

typedef __bf16 bf16;
typedef __attribute__((ext_vector_type(8))) __bf16 bf16x8;
typedef __attribute__((ext_vector_type(4))) __bf16 bf16x4;
typedef __attribute__((ext_vector_type(4))) float f32x4;

#define B_    64
#define N_    197
#define C_    768
#define H_    12
#define HD_   64
#define SCALE_ 0.125f
#define NM_   (N_*N_)         // 38809
#define M_    (B_*N_)         // 12608
#define NEGI_ (-30000.0f)
#define VTP_  200             // vbufT / rpbT row pad

#define GLL16(gptr, lptr) \
  __builtin_amdgcn_global_load_lds((const __attribute__((address_space(1))) unsigned int*)(gptr), \
                                   (__attribute__((address_space(3))) unsigned int*)(lptr), 16, 0, 0)

// ---------------- fused prep: cast x/proj_w, W_eff + bias, rpbT ----------------
// blocks [0,5016): cast; [5016,11928): weff; [11928,13748): rpbT
__global__ __launch_bounds__(256) void prep_kernel(
    const float* __restrict__ x, const float* __restrict__ pw,
    const float* __restrict__ qkv_w, const float* __restrict__ q_bias, const float* __restrict__ v_bias,
    const float* __restrict__ qa, const float* __restrict__ qb,
    const float* __restrict__ ka, const float* __restrict__ kb,
    const float* __restrict__ va, const float* __restrict__ vb,
    const float* __restrict__ table, const int* __restrict__ rpi,
    bf16* __restrict__ xbf, bf16* __restrict__ pwbf,
    bf16* __restrict__ weff, float* __restrict__ biasf, bf16* __restrict__ rpbT)
{
  const int bid = blockIdx.x, tid = threadIdx.x;
  if (bid < 5016) {
    const size_t n1 = (size_t)M_ * C_;   // 9,682,944
    size_t i8 = ((size_t)bid * 256 + tid) * 8;
    const float* src; bf16* dst; size_t off;
    if (i8 < n1) { src = x;  dst = xbf;  off = i8; }
    else         { src = pw; dst = pwbf; off = i8 - n1; }
    float4 f0 = *(const float4*)(src + off);
    float4 f1 = *(const float4*)(src + off + 4);
    bf16x8 v8;
    v8[0] = (bf16)f0.x; v8[1] = (bf16)f0.y; v8[2] = (bf16)f0.z; v8[3] = (bf16)f0.w;
    v8[4] = (bf16)f1.x; v8[5] = (bf16)f1.y; v8[6] = (bf16)f1.z; v8[7] = (bf16)f1.w;
    *(bf16x8*)(dst + off) = v8;
  } else if (bid < 11928) {
    int idx = (bid - 5016) * 256 + tid;          // < 1,769,472 exact
    int d = idx / C_, c = idx - d * C_;
    int sel = d / C_, dd = d - sel * C_;
    const float* a  = (sel == 0) ? qa : (sel == 1) ? ka : va;
    const float* bw = (sel == 0) ? qb : (sel == 1) ? kb : vb;
    float acc = qkv_w[idx];
#pragma unroll
    for (int r = 0; r < 24; ++r)
      acc += bw[dd * 24 + r] * a[r * C_ + c];
    weff[idx] = (bf16)acc;
    if (c == 0)
      biasf[d] = (sel == 0) ? q_bias[dd] : (sel == 2) ? v_bias[dd] : 0.0f;
  } else {
    int idx = (bid - 11928) * 256 + tid;
    if (idx < H_ * NM_) {
      int h = idx / NM_, nm = idx - h * NM_;
      int n = nm / N_, m = nm - n * N_;
      rpbT[((size_t)h * N_ + m) * VTP_ + n] = (bf16)table[rpi[nm] * H_ + h];
    }
  }
}

// ---------------- gemm_qkv: 256x256 tile, BK=64, 8-wave, 8-phase counted-vmcnt pipeline ----------
// C[M,Nn] = A[M,K] @ B[Nn,K]^T + bias, scatter epilogue to q/k/vT (old MODE 0 semantics).
// Structure per guide §5 template (T2 swizzle + T3/T4 counted vmcnt + T5 setprio):
//   per K-tile 4 phases: {ds_read frag subtile ; stage 1 half-tile ; barrier ; lgkmcnt(0) ;
//                         setprio(1) ; 16 MFMA ; setprio(0) ; barrier}
//   stage stream per window t: B(t+1)-lo, B(t+1)-hi, A(t+2)-lo, A(t+2)-hi  (2 GLL16/thread each)
//   window-end wait: vmcnt(4) (leaves A(t+2) in flight), vmcnt(0) for last two windows.
// Race safety: every LDS region's ds_reads complete (lgkmcnt(0)+barrier) at least one barrier
// before the tile-(t+2) stage that overwrites it (A-lo read ph1 / written ph3; A-hi read ph3 /
// written ph4; B regions of buf p only written in window t+1).
__global__ __launch_bounds__(512, 2) void gemm_qkv(
    const bf16* __restrict__ A, const bf16* __restrict__ Bw,
    const float* __restrict__ biasp, int M, int Nn, int K,
    bf16* __restrict__ qo, bf16* __restrict__ ko, bf16* __restrict__ vo)
{
  __shared__ __align__(16) bf16 lds[2][2][256 * 64];   // [buf][A=0/B=1][256 rows x 64 cols], 128 KiB
  const int tid = threadIdx.x;
  const int lane = tid & 63, w = tid >> 6;
  const int l15 = lane & 15, quad = lane >> 4;
  const int wm = w & 1;        // M-half of wave (0/1) -> rows wm*128..wm*128+127
  const int wn = w >> 1;       // N-quarter (0..3)     -> cols wn*64..wn*64+63

  // bijective XCD-aware block swizzle (m204): contiguous wg-chunks per XCD
  const int nwg = gridDim.x, orig = blockIdx.x;
  const int xcd = orig & 7, hi = orig >> 3;
  const int qq = nwg >> 3, rr = nwg & 7;
  const int wg = (xcd < rr ? xcd * (qq + 1) : rr * (qq + 1) + (xcd - rr) * qq) + hi;
  const int ntx = Nn >> 8;
  const int rowB0 = (wg % ntx) * 256;
  const int rowA0 = (wg / ntx) * 256;

  const int NT = K >> 6;
  const int Mm = M - 1, Nm = Nn - 1;

  f32x4 acc[8][4] = {};

  // one 128-row half-tile of one matrix: 512 thr x 2 x 16B = 16 KiB
  // LDS dest linear (wave-uniform base + lane*16); swizzle applied on the GLOBAL column (rule #21)
  auto stage = [&](const bf16* g, int grow0, int rmax, int kt, bf16* dst) {
#pragma unroll
    for (int i = 0; i < 2; ++i) {
      int lin = i * 512 + tid;                    // 0..1023
      int r = lin >> 3, cb = lin & 7;
      int gr = grow0 + r; if (gr > rmax) gr = rmax;
      GLL16(g + (size_t)gr * K + kt + ((cb ^ (r & 7)) << 3), dst + lin * 8);
    }
  };

  // prologue: A(0)lo, A(0)hi, B(0)lo, B(0)hi, A(1)lo, A(1)hi  (12 loads)
  stage(A,  rowA0,       Mm, 0, &lds[0][0][0]);
  stage(A,  rowA0 + 128, Mm, 0, &lds[0][0][128 * 64]);
  stage(Bw, rowB0,       Nm, 0, &lds[0][1][0]);
  stage(Bw, rowB0 + 128, Nm, 0, &lds[0][1][128 * 64]);
  if (NT > 1) {
    stage(A, rowA0,       Mm, 64, &lds[1][0][0]);
    stage(A, rowA0 + 128, Mm, 64, &lds[1][0][128 * 64]);
  }
  asm volatile("s_waitcnt vmcnt(4)" ::: "memory");   // A(0),B(0) landed; A(1) in flight
  __builtin_amdgcn_s_barrier();

  bf16x8 af[4][2], bl[2][2], bh[2][2];

  for (int t = 0; t < NT; ++t) {
    const int p = t & 1, q = p ^ 1;
    const bf16* As = &lds[p][0][0];
    const bf16* Bs = &lds[p][1][0];
    auto rdA = [&](int mf, int kk) {
      int row = wm * 128 + mf * 16 + l15;
      int cb = kk * 4 + quad;
      return *(const bf16x8*)(As + row * 64 + ((cb ^ (l15 & 7)) << 3));
    };
    auto rdB = [&](int nf, int kk) {
      int row = wn * 64 + nf * 16 + l15;
      int cb = kk * 4 + quad;
      return *(const bf16x8*)(Bs + row * 64 + ((cb ^ (l15 & 7)) << 3));
    };

    // ---- phase 1: read A-lo + B-lo frags ; stage B(t+1)-lo ; MFMA Q(0,0)
#pragma unroll
    for (int mf = 0; mf < 4; ++mf) { af[mf][0] = rdA(mf, 0); af[mf][1] = rdA(mf, 1); }
#pragma unroll
    for (int nf = 0; nf < 2; ++nf) { bl[nf][0] = rdB(nf, 0); bl[nf][1] = rdB(nf, 1); }
    if (t + 1 < NT) stage(Bw, rowB0, Nm, (t + 1) * 64, &lds[q][1][0]);
    __builtin_amdgcn_s_barrier();
    asm volatile("s_waitcnt lgkmcnt(0)" ::: "memory");
    __builtin_amdgcn_s_setprio(1);
#pragma unroll
    for (int mf = 0; mf < 4; ++mf)
#pragma unroll
      for (int nf = 0; nf < 2; ++nf)
#pragma unroll
        for (int kk = 0; kk < 2; ++kk)
          acc[mf][nf] = __builtin_amdgcn_mfma_f32_16x16x32_bf16(af[mf][kk], bl[nf][kk], acc[mf][nf], 0, 0, 0);
    __builtin_amdgcn_s_setprio(0);
    __builtin_amdgcn_s_barrier();

    // ---- phase 2: read B-hi frags ; stage B(t+1)-hi ; MFMA Q(0,1)
#pragma unroll
    for (int nf = 0; nf < 2; ++nf) { bh[nf][0] = rdB(nf + 2, 0); bh[nf][1] = rdB(nf + 2, 1); }
    if (t + 1 < NT) stage(Bw, rowB0 + 128, Nm, (t + 1) * 64, &lds[q][1][128 * 64]);
    __builtin_amdgcn_s_barrier();
    asm volatile("s_waitcnt lgkmcnt(0)" ::: "memory");
    __builtin_amdgcn_s_setprio(1);
#pragma unroll
    for (int mf = 0; mf < 4; ++mf)
#pragma unroll
      for (int nf = 0; nf < 2; ++nf)
#pragma unroll
        for (int kk = 0; kk < 2; ++kk)
          acc[mf][nf + 2] = __builtin_amdgcn_mfma_f32_16x16x32_bf16(af[mf][kk], bh[nf][kk], acc[mf][nf + 2], 0, 0, 0);
    __builtin_amdgcn_s_setprio(0);
    __builtin_amdgcn_s_barrier();

    // ---- phase 3: read A-hi frags ; stage A(t+2)-lo ; MFMA Q(1,1)
#pragma unroll
    for (int mf = 0; mf < 4; ++mf) { af[mf][0] = rdA(mf + 4, 0); af[mf][1] = rdA(mf + 4, 1); }
    if (t + 2 < NT) stage(A, rowA0, Mm, (t + 2) * 64, &lds[p][0][0]);
    __builtin_amdgcn_s_barrier();
    asm volatile("s_waitcnt lgkmcnt(0)" ::: "memory");
    __builtin_amdgcn_s_setprio(1);
#pragma unroll
    for (int mf = 0; mf < 4; ++mf)
#pragma unroll
      for (int nf = 0; nf < 2; ++nf)
#pragma unroll
        for (int kk = 0; kk < 2; ++kk)
          acc[mf + 4][nf + 2] = __builtin_amdgcn_mfma_f32_16x16x32_bf16(af[mf][kk], bh[nf][kk], acc[mf + 4][nf + 2], 0, 0, 0);
    __builtin_amdgcn_s_setprio(0);
    __builtin_amdgcn_s_barrier();

    // ---- phase 4: re-read B-lo frags ; stage A(t+2)-hi ; MFMA Q(1,0) ; counted vmcnt
#pragma unroll
    for (int nf = 0; nf < 2; ++nf) { bl[nf][0] = rdB(nf, 0); bl[nf][1] = rdB(nf, 1); }
    if (t + 2 < NT) stage(A, rowA0 + 128, Mm, (t + 2) * 64, &lds[p][0][128 * 64]);
    __builtin_amdgcn_s_barrier();
    asm volatile("s_waitcnt lgkmcnt(0)" ::: "memory");
    __builtin_amdgcn_s_setprio(1);
#pragma unroll
    for (int mf = 0; mf < 4; ++mf)
#pragma unroll
      for (int nf = 0; nf < 2; ++nf)
#pragma unroll
        for (int kk = 0; kk < 2; ++kk)
          acc[mf + 4][nf] = __builtin_amdgcn_mfma_f32_16x16x32_bf16(af[mf][kk], bl[nf][kk], acc[mf + 4][nf], 0, 0, 0);
    __builtin_amdgcn_s_setprio(0);
    if (t >= NT - 2) asm volatile("s_waitcnt vmcnt(0)" ::: "memory");
    else             asm volatile("s_waitcnt vmcnt(4)" ::: "memory");
    __builtin_amdgcn_s_barrier();
  }

  // ---- epilogue: scatter q(xSCALE)/k -> [B,H,N,HD]; v -> transposed [B,H,HD,VTP_]
#pragma unroll
  for (int mf = 0; mf < 8; ++mf) {
#pragma unroll
    for (int nf = 0; nf < 4; ++nf) {
#pragma unroll
      for (int r = 0; r < 4; ++r) {
        int m = rowA0 + wm * 128 + mf * 16 + quad * 4 + r;
        int d = rowB0 + wn * 64 + nf * 16 + l15;
        if (m >= M) continue;
        float v = acc[mf][nf][r] + biasp[d];
        int b = m / N_, n = m - b * N_;
        int sel = d / C_, dd = d - sel * C_;
        int h = dd >> 6, hd = dd & 63;
        if (sel == 0)
          qo[(((size_t)b * H_ + h) * N_ + n) * HD_ + hd] = (bf16)(v * SCALE_);
        else if (sel == 1)
          ko[(((size_t)b * H_ + h) * N_ + n) * HD_ + hd] = (bf16)v;
        else
          vo[(((size_t)b * H_ + h) * HD_ + hd) * VTP_ + n] = (bf16)v;   // transposed
      }
    }
  }
}

// ---------------- gemm_bt (kept for proj GEMM, MODE 1 only) ----------------
// grid: (Nn/128, ceil(M/128)) 2D, N-tile fastest.
// __launch_bounds__(256,4): force <=128 unified regs/wave -> 4 waves/SIMD.
template<int MODE>
__global__ __launch_bounds__(256, 4) void gemm_bt(
    const bf16* __restrict__ A, const bf16* __restrict__ Bw,
    const float* __restrict__ biasp,
    float* __restrict__ Coutf, int M, int Nn, int K,
    bf16* __restrict__ qo, bf16* __restrict__ ko, bf16* __restrict__ vo)
{
  __shared__ __align__(16) bf16 As[128 * 64];
  __shared__ __align__(16) bf16 Bs[128 * 64];
  const int tid = threadIdx.x;
  const int lane = tid & 63, w = tid >> 6;
  const int l15 = lane & 15, quad = lane >> 4;
  const int wm = (w & 1) * 64, wn = (w >> 1) * 64;
  const int rowA0 = blockIdx.y * 128;   // M-tile
  const int rowB0 = blockIdx.x * 128;   // N-tile (fastest-varying)

  f32x4 acc[4][4] = {};

  for (int kt = 0; kt < K; kt += 64) {
#pragma unroll
    for (int i = 0; i < 4; ++i) {
      int lin = (w * 4 + i) * 64 + lane;       // 0..1023
      int r  = lin >> 3;                       // 0..127
      int cb = lin & 7;                        // LDS column block
      int csw = ((cb ^ (r & 7)) << 3);         // swizzled global column (elems)
      int ga = rowA0 + r; if (ga > M - 1) ga = M - 1;
      GLL16(A + (size_t)ga * K + kt + csw, &As[lin * 8]);
      int gb = rowB0 + r; if (gb > Nn - 1) gb = Nn - 1;
      GLL16(Bw + (size_t)gb * K + kt + csw, &Bs[lin * 8]);
    }
    __syncthreads();
#pragma unroll
    for (int ks = 0; ks < 2; ++ks) {
      const int cb = ks * 4 + quad;            // k-block 0..7
      const int sw = (cb ^ (l15 & 7)) << 3;
      bf16x8 af[4], bfr[4];
#pragma unroll
      for (int i = 0; i < 4; ++i)
        af[i] = *(const bf16x8*)(&As[(wm + i * 16 + l15) * 64 + sw]);
#pragma unroll
      for (int j = 0; j < 4; ++j)
        bfr[j] = *(const bf16x8*)(&Bs[(wn + j * 16 + l15) * 64 + sw]);
#pragma unroll
      for (int i = 0; i < 4; ++i)
#pragma unroll
        for (int j = 0; j < 4; ++j)
          acc[i][j] = __builtin_amdgcn_mfma_f32_16x16x32_bf16(af[i], bfr[j], acc[i][j], 0, 0, 0);
    }
    __syncthreads();
  }

#pragma unroll
  for (int i = 0; i < 4; ++i) {
#pragma unroll
    for (int j = 0; j < 4; ++j) {
#pragma unroll
      for (int r = 0; r < 4; ++r) {
        int m = rowA0 + wm + i * 16 + quad * 4 + r;
        int d = rowB0 + wn + j * 16 + l15;
        if (m >= M) continue;
        float v = acc[i][j][r] + biasp[d];
        if (MODE == 0) {
          int b = m / N_, n = m - b * N_;
          int sel = d / C_, dd = d - sel * C_;
          int h = dd >> 6, hd = dd & 63;
          if (sel == 0)
            qo[(((size_t)b * H_ + h) * N_ + n) * HD_ + hd] = (bf16)(v * SCALE_);
          else if (sel == 1)
            ko[(((size_t)b * H_ + h) * N_ + n) * HD_ + hd] = (bf16)v;
          else
            vo[(((size_t)b * H_ + h) * HD_ + hd) * VTP_ + n] = (bf16)v;   // transposed
        } else {
          Coutf[(size_t)m * Nn + d] = v;
        }
      }
    }
  }
}

// ---------------- attention: per (qtile, h, b) block, barrier-free, max-free softmax ----------------
#define SW 232   // P row stride (bf16 elems); PV consumes cols 0..223
__global__ __launch_bounds__(256) void attn_kernel(
    const bf16* __restrict__ q, const bf16* __restrict__ k, const bf16* __restrict__ vT_g,
    const bf16* __restrict__ rpbT, bf16* __restrict__ out)
{
  __shared__ __align__(16) bf16 s_lds[64 * SW];   // P tile (each wave owns its 16 rows)

  const int tid = threadIdx.x;
  const int lane = tid & 63, w = tid >> 6;
  const int l15 = lane & 15, quad = lane >> 4;
  const int qt = blockIdx.x, h = blockIdx.y, b = blockIdx.z;
  const size_t bh = ((size_t)b * H_ + h) * N_ * HD_;
  const bf16* qb = q + bh;
  const bf16* kb = k + bh;
  const bf16* vg = vT_g + ((size_t)b * H_ + h) * HD_ * VTP_;

  // zero this wave's P pad cols [208,224)  (QK pass writes cols 0..207)
  if (quad < 2)
    *(uint4*)(&s_lds[(w * 16 + l15) * SW + 208 + quad * 8]) = (uint4){0, 0, 0, 0};

  // ---- fused pass: S = Q K^T + rpb, P = exp(S), rowsum ----
  const int row0 = qt * 64 + w * 16;
  int qm = row0 + l15; if (qm > N_ - 1) qm = N_ - 1;
  bf16x8 aq0 = *(const bf16x8*)(qb + qm * HD_ + quad * 8);
  bf16x8 aq1 = *(const bf16x8*)(qb + qm * HD_ + 32 + quad * 8);

  int rbase = row0 + quad * 4; if (rbase > N_ - 1) rbase = N_ - 1;

  float sum[4] = {0.f, 0.f, 0.f, 0.f};
#pragma unroll
  for (int jt = 0; jt < 13; ++jt) {
    int col = jt * 16 + l15;
    int kn = col; if (kn > N_ - 1) kn = N_ - 1;
    bf16x8 bk0 = *(const bf16x8*)(kb + kn * HD_ + quad * 8);
    bf16x8 bk1 = *(const bf16x8*)(kb + kn * HD_ + 32 + quad * 8);
    bf16x4 rb = *(const bf16x4*)(rpbT + ((size_t)h * N_ + kn) * VTP_ + rbase);
    f32x4 s = {0.f, 0.f, 0.f, 0.f};
    s = __builtin_amdgcn_mfma_f32_16x16x32_bf16(aq0, bk0, s, 0, 0, 0);
    s = __builtin_amdgcn_mfma_f32_16x16x32_bf16(aq1, bk1, s, 0, 0, 0);
#pragma unroll
    for (int r = 0; r < 4; ++r) {
      int row = row0 + quad * 4 + r;
      // scores are O(10); pads get -30000 -> exp underflows to exactly 0
      float sv = (col < N_ && row < N_) ? (s[r] + (float)rb[r]) : NEGI_;
      float p = __expf(sv);
      bf16 pb = (bf16)p;
      s_lds[(w * 16 + quad * 4 + r) * SW + col] = pb;
      sum[r] += (float)pb;
    }
  }

  // prefetch phase-B kk=0 V fragments into the shuffle-latency shadow
  bf16x8 bv0[4];
#pragma unroll
  for (int j2 = 0; j2 < 4; ++j2)
    bv0[j2] = *(const bf16x8*)(vg + (j2 * 16 + l15) * VTP_ + quad * 8);

#pragma unroll
  for (int r = 0; r < 4; ++r) {
    sum[r] += __shfl_xor(sum[r], 1);
    sum[r] += __shfl_xor(sum[r], 2);
    sum[r] += __shfl_xor(sum[r], 4);
    sum[r] += __shfl_xor(sum[r], 8);
  }
  float inv[4];
#pragma unroll
  for (int r = 0; r < 4; ++r) inv[r] = 1.0f / fmaxf(sum[r], 1e-20f);

  // ---- phase B: O = P @ V  (V^T fragments straight from global; pads hit exact-zero P) ----
  f32x4 o[4] = {};
  {
    bf16x8 ap = *(const bf16x8*)(&s_lds[(w * 16 + l15) * SW + quad * 8]);
#pragma unroll
    for (int j2 = 0; j2 < 4; ++j2)
      o[j2] = __builtin_amdgcn_mfma_f32_16x16x32_bf16(ap, bv0[j2], o[j2], 0, 0, 0);
  }
#pragma unroll
  for (int kk = 1; kk < 7; ++kk) {
    bf16x8 ap = *(const bf16x8*)(&s_lds[(w * 16 + l15) * SW + kk * 32 + quad * 8]);
#pragma unroll
    for (int j2 = 0; j2 < 4; ++j2) {
      bf16x8 bv = *(const bf16x8*)(vg + (j2 * 16 + l15) * VTP_ + kk * 32 + quad * 8);
      o[j2] = __builtin_amdgcn_mfma_f32_16x16x32_bf16(ap, bv, o[j2], 0, 0, 0);
    }
  }
#pragma unroll
  for (int j2 = 0; j2 < 4; ++j2) {
#pragma unroll
    for (int r = 0; r < 4; ++r) {
      int row = qt * 64 + w * 16 + quad * 4 + r;
      int hd = j2 * 16 + l15;
      if (row < N_)
        out[((size_t)b * N_ + row) * C_ + h * HD_ + hd] = (bf16)(o[j2][r] * inv[r]);
    }
  }
}

// ---------------- launch ----------------
extern "C" void kernel_launch(void* const* d_in, const int* in_sizes, int n_in,
                              void* d_out, int out_size, void* d_ws, size_t ws_size,
                              hipStream_t stream)
{
  const float* x      = (const float*)d_in[0];
  const float* qkv_w  = (const float*)d_in[1];
  const float* q_bias = (const float*)d_in[2];
  const float* v_bias = (const float*)d_in[3];
  const float* q_la   = (const float*)d_in[4];
  const float* q_lb   = (const float*)d_in[5];
  const float* k_la   = (const float*)d_in[6];
  const float* k_lb   = (const float*)d_in[7];
  const float* v_la   = (const float*)d_in[8];
  const float* v_lb   = (const float*)d_in[9];
  const float* rpt    = (const float*)d_in[10];
  const float* proj_w = (const float*)d_in[11];
  const float* proj_b = (const float*)d_in[12];
  const int*   rpi    = (const int*)d_in[13];
  float* out = (float*)d_out;

  char* ws = (char*)d_ws;
  // layout (16B-aligned); xbf dead after gemm_qkv, reused as aout
  bf16*  xbf   = (bf16*)(ws);                         // 19,365,888 B
  bf16*  aout  = (bf16*)(ws);                         // alias
  bf16*  weff  = (bf16*)(ws + 19365888);              //  3,538,944 B
  float* biasf = (float*)(ws + 22904832);             //      9,216 B
  bf16*  pwbf  = (bf16*)(ws + 22914048);              //  1,179,648 B
  bf16*  qbuf  = (bf16*)(ws + 24093696);              // 19,365,888 B
  bf16*  kbuf  = (bf16*)(ws + 43459584);              // 19,365,888 B
  bf16*  vbufT = (bf16*)(ws + 62825472);              // 19,660,800 (+128 slack)
  bf16*  rpbT  = (bf16*)(ws + 82486400);              // 945,600
  // total ws use ≈ 83.4 MB

  prep_kernel<<<13748, 256, 0, stream>>>(
      x, proj_w, qkv_w, q_bias, v_bias, q_la, q_lb, k_la, k_lb, v_la, v_lb,
      rpt, rpi, xbf, pwbf, weff, biasf, rpbT);

  // 9 N-tiles x 50 M-tiles = 450 blocks, 512 threads (8 waves), 128 KiB LDS, 1 block/CU
  gemm_qkv<<<dim3(450), 512, 0, stream>>>(
      xbf, weff, biasf, M_, 3 * C_, C_, qbuf, kbuf, vbufT);

  attn_kernel<<<dim3(4, H_, B_), 256, 0, stream>>>(qbuf, kbuf, vbufT, rpbT, aout);

  gemm_bt<1><<<dim3(6, 99), 256, 0, stream>>>(
      aout, pwbf, proj_b, out, M_, C_, C_, nullptr, nullptr, nullptr);
}